// Round 5
// baseline (1290.537 us; speedup 1.0000x reference)
//
#include <hip/hip_runtime.h>
#include <hip/hip_bf16.h>

typedef unsigned short u16;
typedef unsigned int u32;
typedef __attribute__((ext_vector_type(8))) short short8;
typedef __attribute__((ext_vector_type(4))) float floatx4;

__device__ __forceinline__ u16 f2bf(float f) {
  u32 x = __float_as_uint(f);
  x += 0x7FFFu + ((x >> 16) & 1u);
  return (u16)(x >> 16);
}
__device__ __forceinline__ float bf2f(u16 u) { return __uint_as_float(((u32)u) << 16); }

__device__ __forceinline__ void mfma8(floatx4& acc, short8 a, short8 b) {
  acc = __builtin_amdgcn_mfma_f32_16x16x32_bf16(a, b, acc, 0, 0, 0);
}

#define ZACC24(A)                    \
  do {                               \
    for (int _i = 0; _i < 2; ++_i)   \
      for (int _j = 0; _j < 4; ++_j) \
        A[_i][_j] = (floatx4){0.f, 0.f, 0.f, 0.f}; \
  } while (0)

// 32-row x 64-col (4 n-tiles) MFMA tile, A (bf16) in LDS [32][lda], B (bf16) global [N][ldw].
// Fragment layout verified in round 4: A lane holds A[m=lane&15][k=(lane>>4)*8+j];
// C/D: col=lane&15, row=(lane>>4)*4+reg.
__device__ __forceinline__ void gemm_tile_lA(floatx4 acc[2][4], const u16* Abf, int lda,
                                             const u16* W, int ldw, int n0, int K, int lane) {
  const int rr = lane & 15, q = lane >> 4;
  for (int k0 = 0; k0 < K; k0 += 32) {
    short8 a0 = *(const short8*)(Abf + rr * lda + k0 + q * 8);
    short8 a1 = *(const short8*)(Abf + (16 + rr) * lda + k0 + q * 8);
#pragma unroll
    for (int nt = 0; nt < 4; ++nt) {
      short8 b = *(const short8*)(W + (size_t)(n0 + nt * 16 + rr) * ldw + k0 + q * 8);
      mfma8(acc[0][nt], a0, b);
      mfma8(acc[1][nt], a1, b);
    }
  }
}

// Same but A (bf16) directly from global rows m0..m0+31.
__device__ __forceinline__ void gemm_tile_gA(floatx4 acc[2][4], const u16* Ag, int lda, int m0,
                                             const u16* W, int ldw, int n0, int K, int lane) {
  const int rr = lane & 15, q = lane >> 4;
  for (int k0 = 0; k0 < K; k0 += 32) {
    short8 a0 = *(const short8*)(Ag + (size_t)(m0 + rr) * lda + k0 + q * 8);
    short8 a1 = *(const short8*)(Ag + (size_t)(m0 + 16 + rr) * lda + k0 + q * 8);
#pragma unroll
    for (int nt = 0; nt < 4; ++nt) {
      short8 b = *(const short8*)(W + (size_t)(n0 + nt * 16 + rr) * ldw + k0 + q * 8);
      mfma8(acc[0][nt], a0, b);
      mfma8(acc[1][nt], a1, b);
    }
  }
}

__device__ __forceinline__ void store_cd_bf16(floatx4 acc[2][4], u16* dst, int ld, int m0,
                                              int n0, const float* bias, int relu, int lane) {
  const int rr = lane & 15, q = lane >> 4;
#pragma unroll
  for (int mt = 0; mt < 2; ++mt)
#pragma unroll
    for (int nt = 0; nt < 4; ++nt) {
      int col = n0 + nt * 16 + rr;
      float bv = bias[col];
#pragma unroll
      for (int r = 0; r < 4; ++r) {
        int row = m0 + mt * 16 + q * 4 + r;
        float v = acc[mt][nt][r] + bv;
        if (relu) v = fmaxf(v, 0.f);
        dst[(size_t)row * ld + col] = f2bf(v);
      }
    }
}

// ---------------- kernel 0: convert all GEMM weights fp32 -> bf16 in ws ----------
struct WConvArgs {
  const float* src[8];
  u16* dst[8];
  int cnt[8];
};
__global__ __launch_bounds__(256) void wconv_kernel(WConvArgs a) {
  int tid = blockIdx.x * 256 + threadIdx.x;
  int stride = gridDim.x * 256;
  for (int s = 0; s < 8; ++s) {
    const float* src = a.src[s];
    u16* dst = a.dst[s];
    int n4 = a.cnt[s] >> 2;
    for (int i = tid; i < n4; i += stride) {
      float4 v = ((const float4*)src)[i];
      ushort4 o;
      o.x = f2bf(v.x); o.y = f2bf(v.y); o.z = f2bf(v.z); o.w = f2bf(v.w);
      ((ushort4*)dst)[i] = o;
    }
  }
}

// ---------------- kernel 1: embed gather + QKV(layer0) ----------------
__global__ __launch_bounds__(256) void embed_qkv_kernel(const int* __restrict__ ids,
    const float* __restrict__ emb, float* __restrict__ x, const u16* __restrict__ qkvw,
    const float* __restrict__ qkvb, u16* __restrict__ qkvbf) {
  __shared__ u16 Albs[32 * 256];
  const int rb = blockIdx.x, t = threadIdx.x, w = t >> 6, lane = t & 63;
  const int m0 = rb * 32;
  for (int r = 0; r < 32; ++r) {
    int row = m0 + r;
    float v = emb[(size_t)ids[row] * 256 + t];
    x[(size_t)row * 256 + t] = v;
    Albs[r * 256 + t] = f2bf(v);
  }
  __syncthreads();
  for (int g = 0; g < 3; ++g) {
    floatx4 acc[2][4];
    ZACC24(acc);
    int n0 = w * 192 + g * 64;
    gemm_tile_lA(acc, Albs, 256, qkvw, 256, n0, 256, lane);
    store_cd_bf16(acc, qkvbf, 768, m0, n0, qkvb, 0, lane);
  }
}

// ---------------- attention: bf16 qkv in, bf16 o out (fp32 internal) ----------------
__global__ __launch_bounds__(256) void attn_kernel(const u16* __restrict__ qkv,
    const int* __restrict__ mask, u16* __restrict__ o) {
  __shared__ float Klds[8192];
  __shared__ float Vlds[8192];
  const int blk = blockIdx.x;  // 512 = 4b * 4h * 32 qgroups
  const int b = blk >> 7, h = (blk >> 5) & 3, qg = blk & 31;
  const int t = threadIdx.x;
  for (int i = t; i < 8192; i += 256) {
    int s = i >> 6, d = i & 63;
    size_t base = (size_t)(b * 128 + s) * 768 + h * 64 + d;
    Klds[(s << 6) + (d ^ (s & 31))] = bf2f(qkv[base + 256]);
    Vlds[i] = bf2f(qkv[base + 512]);
  }
  __syncthreads();
  const int wave = t >> 6, lane = t & 63;
  const int q = qg * 4 + wave;
  float qv = bf2f(qkv[(size_t)(b * 128 + q) * 768 + h * 64 + lane]);
  const int m0i = mask[b * 128 + lane];
  const int m1i = mask[b * 128 + 64 + lane];
  float s0 = 0.f, s1 = 0.f;
  const int sw = lane & 31;
  for (int d = 0; d < 64; ++d) {
    float qd = __shfl(qv, d);
    s0 += qd * Klds[(lane << 6) + (d ^ sw)];
    s1 += qd * Klds[((lane + 64) << 6) + (d ^ sw)];
  }
  s0 *= 0.125f; s1 *= 0.125f;
  if (m0i == 0) s0 = -1000000000.0f;
  if (m1i == 0) s1 = -1000000000.0f;
  float m = fmaxf(s0, s1);
  for (int off = 32; off; off >>= 1) m = fmaxf(m, __shfl_xor(m, off));
  float p0 = expf(s0 - m), p1 = expf(s1 - m);
  float sum = p0 + p1;
  for (int off = 32; off; off >>= 1) sum += __shfl_xor(sum, off);
  float rs = 1.f / sum;
  float acc = 0.f;
  for (int k = 0; k < 64; ++k) acc += __shfl(p0, k) * Vlds[(k << 6) + lane];
  for (int k = 0; k < 64; ++k) acc += __shfl(p1, k) * Vlds[((k + 64) << 6) + lane];
  o[(size_t)(b * 128 + q) * 256 + h * 64 + lane] = f2bf(acc * rs);
}

// ---------------- post1: out-proj + residual + LN1 + FF1(relu) ----------------
__global__ __launch_bounds__(256) void post1_kernel(float* __restrict__ x,
    const u16* __restrict__ obf, const u16* __restrict__ outw, const float* __restrict__ outb,
    const float* __restrict__ g1, const float* __restrict__ b1, const u16* __restrict__ ff1w,
    const float* __restrict__ ff1b, u16* __restrict__ ffbf) {
  __shared__ u16 Albs[32 * 256];
  __shared__ float S[32 * 264];
  const int rb = blockIdx.x, t = threadIdx.x, w = t >> 6, lane = t & 63;
  const int m0 = rb * 32;
  {
    const uint4* src = (const uint4*)(obf + (size_t)m0 * 256);
    uint4* dst = (uint4*)Albs;
    for (int i = t; i < 1024; i += 256) dst[i] = src[i];
  }
  __syncthreads();
  floatx4 acc[2][4];
  ZACC24(acc);
  gemm_tile_lA(acc, Albs, 256, outw, 256, w * 64, 256, lane);
  {
    const int rr = lane & 15, q = lane >> 4;
#pragma unroll
    for (int mt = 0; mt < 2; ++mt)
#pragma unroll
      for (int nt = 0; nt < 4; ++nt) {
        int col = w * 64 + nt * 16 + rr;
        float bv = outb[col];
#pragma unroll
        for (int r = 0; r < 4; ++r) {
          int row = mt * 16 + q * 4 + r;
          S[row * 264 + col] = acc[mt][nt][r] + bv + x[(size_t)(m0 + row) * 256 + col];
        }
      }
  }
  __syncthreads();
  {
    int j = t >> 3, s8 = t & 7;
    float sm = 0.f, sq = 0.f;
    for (int c = s8 * 32; c < s8 * 32 + 32; ++c) {
      float v = S[j * 264 + c];
      sm += v; sq += v * v;
    }
    for (int off = 1; off < 8; off <<= 1) { sm += __shfl_xor(sm, off); sq += __shfl_xor(sq, off); }
    float mean = sm * (1.f / 256.f);
    float var = sq * (1.f / 256.f) - mean * mean;
    float inv = 1.f / sqrtf(fmaxf(var, 0.f) + 1e-5f);
    for (int c = s8 * 32; c < s8 * 32 + 32; ++c) {
      float v = (S[j * 264 + c] - mean) * inv * g1[c] + b1[c];
      x[(size_t)(m0 + j) * 256 + c] = v;
      Albs[j * 256 + c] = f2bf(v);
    }
  }
  __syncthreads();
  for (int gb = 0; gb < 8; ++gb) {
    floatx4 a2[2][4];
    ZACC24(a2);
    int n0 = w * 512 + gb * 64;
    gemm_tile_lA(a2, Albs, 256, ff1w, 256, n0, 256, lane);
    store_cd_bf16(a2, ffbf, 2048, m0, n0, ff1b, 1, lane);
  }
}

// ---------------- post2: FF2 + residual + LN2 (+ next-layer QKV) ----------------
template <int LAST>
__global__ __launch_bounds__(256) void post2_kernel(const u16* __restrict__ ffbf,
    const u16* __restrict__ ff2w, const float* __restrict__ ff2b, const float* __restrict__ g2,
    const float* __restrict__ b2, float* __restrict__ x, const u16* __restrict__ qkvw,
    const float* __restrict__ qkvb, u16* __restrict__ qkvbf) {
  __shared__ u16 Albs[32 * 256];
  __shared__ float S[32 * 264];
  const int rb = blockIdx.x, t = threadIdx.x, w = t >> 6, lane = t & 63;
  const int m0 = rb * 32;
  floatx4 acc[2][4];
  ZACC24(acc);
  gemm_tile_gA(acc, ffbf, 2048, m0, ff2w, 2048, w * 64, 2048, lane);
  {
    const int rr = lane & 15, q = lane >> 4;
#pragma unroll
    for (int mt = 0; mt < 2; ++mt)
#pragma unroll
      for (int nt = 0; nt < 4; ++nt) {
        int col = w * 64 + nt * 16 + rr;
        float bv = ff2b[col];
#pragma unroll
        for (int r = 0; r < 4; ++r) {
          int row = mt * 16 + q * 4 + r;
          S[row * 264 + col] = acc[mt][nt][r] + bv + x[(size_t)(m0 + row) * 256 + col];
        }
      }
  }
  __syncthreads();
  {
    int j = t >> 3, s8 = t & 7;
    float sm = 0.f, sq = 0.f;
    for (int c = s8 * 32; c < s8 * 32 + 32; ++c) {
      float v = S[j * 264 + c];
      sm += v; sq += v * v;
    }
    for (int off = 1; off < 8; off <<= 1) { sm += __shfl_xor(sm, off); sq += __shfl_xor(sq, off); }
    float mean = sm * (1.f / 256.f);
    float var = sq * (1.f / 256.f) - mean * mean;
    float inv = 1.f / sqrtf(fmaxf(var, 0.f) + 1e-5f);
    for (int c = s8 * 32; c < s8 * 32 + 32; ++c) {
      float v = (S[j * 264 + c] - mean) * inv * g2[c] + b2[c];
      x[(size_t)(m0 + j) * 256 + c] = v;
      Albs[j * 256 + c] = f2bf(v);
    }
  }
  __syncthreads();
  if (!LAST) {
    for (int g = 0; g < 3; ++g) {
      floatx4 a2[2][4];
      ZACC24(a2);
      int n0 = w * 192 + g * 64;
      gemm_tile_lA(a2, Albs, 256, qkvw, 256, n0, 256, lane);
      store_cd_bf16(a2, qkvbf, 768, m0, n0, qkvb, 0, lane);
    }
  }
}

// ---------------- masked mean pool -> pooled[4][256] ----------------
__global__ void pool_kernel(const float* __restrict__ x, const int* __restrict__ mask,
                            float* __restrict__ pooled) {
  int b = blockIdx.x, d = threadIdx.x;
  float s = 0.f, c = 0.f;
  for (int ss = 0; ss < 128; ++ss) {
    float m = (float)mask[b * 128 + ss];
    s += m * x[(size_t)(b * 128 + ss) * 256 + d];
    c += m;
  }
  pooled[b * 256 + d] = s / fmaxf(c, 1.f);
}

// ---------------- projection GEMV: pe (bf16 out) ----------------
__global__ __launch_bounds__(256) void proj_kernel(const float* __restrict__ pooled,
    const float* __restrict__ W, const float* __restrict__ bias, u16* __restrict__ pebf) {
  __shared__ float pl[1024];
  int t = threadIdx.x;
  for (int i = t; i < 1024; i += 256) pl[i] = pooled[i];
  __syncthreads();
  int wave = t >> 6, lane = t & 63;
  int half = lane >> 5, sl = lane & 31;
  int row = blockIdx.x * 8 + wave * 2 + half;
  float4 w0 = *(const float4*)(W + (size_t)row * 256 + sl * 8);
  float4 w1 = *(const float4*)(W + (size_t)row * 256 + sl * 8 + 4);
  float a0, a1, a2, a3;
#pragma unroll
  for (int bb = 0; bb < 4; ++bb) {
    const float* pp = &pl[bb * 256 + sl * 8];
    float v = w0.x * pp[0] + w0.y * pp[1] + w0.z * pp[2] + w0.w * pp[3]
            + w1.x * pp[4] + w1.y * pp[5] + w1.z * pp[6] + w1.w * pp[7];
    if (bb == 0) a0 = v; else if (bb == 1) a1 = v; else if (bb == 2) a2 = v; else a3 = v;
  }
#pragma unroll
  for (int off = 1; off < 32; off <<= 1) {
    a0 += __shfl_xor(a0, off); a1 += __shfl_xor(a1, off);
    a2 += __shfl_xor(a2, off); a3 += __shfl_xor(a3, off);
  }
  if (sl == 0) {
    float bv = bias[row];
    pebf[0 * 114688 + row] = f2bf(a0 + bv);
    pebf[1 * 114688 + row] = f2bf(a1 + bv);
    pebf[2 * 114688 + row] = f2bf(a2 + bv);
    pebf[3 * 114688 + row] = f2bf(a3 + bv);
  }
}

// ---------------- dec1: h = gelu(pe @ w1^T + b1), A and B branches ----------------
__global__ __launch_bounds__(256) void dec1_kernel(const u16* __restrict__ pebf,
    const u16* __restrict__ a1w, const u16* __restrict__ b1w, const float* __restrict__ a1b,
    const float* __restrict__ b1b, u16* __restrict__ hA, u16* __restrict__ hB) {
  const int rb = blockIdx.x, zi = blockIdx.y;
  const u16* W = zi ? b1w : a1w;
  const float* bias = zi ? b1b : a1b;
  u16* dst = zi ? hB : hA;
  const int t = threadIdx.x, w = t >> 6, lane = t & 63;
  const int m0 = rb * 32;
  floatx4 acc[2][4];
  ZACC24(acc);
  gemm_tile_gA(acc, pebf, 512, m0, W, 512, w * 64, 512, lane);
  const int rr = lane & 15, q = lane >> 4;
#pragma unroll
  for (int mt = 0; mt < 2; ++mt)
#pragma unroll
    for (int nt = 0; nt < 4; ++nt) {
      int col = w * 64 + nt * 16 + rr;
      float bv = bias[col];
#pragma unroll
      for (int r = 0; r < 4; ++r) {
        int row = m0 + mt * 16 + q * 4 + r;
        float v = acc[mt][nt][r] + bv;
        v = 0.5f * v * (1.f + erff(v * 0.70710678118654752f));
        dst[(size_t)row * 256 + col] = f2bf(v);
      }
    }
}

// ---------------- dec2A + tile_A writes (out0 A_HID, out1 A_INT) ----------------
// grid (28, 16, 4): rb=32 bp-rows, j = r (0..15), z = rep split.
__global__ __launch_bounds__(256) void dec2a_kernel(const u16* __restrict__ hA,
    const u16* __restrict__ a2w, const float* __restrict__ a2b, const float* __restrict__ scales,
    float* __restrict__ out0, float* __restrict__ out1) {
  __shared__ float tile[32][68];
  const int rb = blockIdx.x, j = blockIdx.y, z = blockIdx.z;
  const int t = threadIdx.x, w = t >> 6, lane = t & 63;
  const int m0 = rb * 32;
  const int mt = w >> 1, ntb = (w & 1) * 2;
  const int rr = lane & 15, q = lane >> 4;
  floatx4 acc[2];
  acc[0] = (floatx4){0.f, 0.f, 0.f, 0.f};
  acc[1] = (floatx4){0.f, 0.f, 0.f, 0.f};
  for (int k0 = 0; k0 < 256; k0 += 32) {
    short8 a = *(const short8*)(hA + (size_t)(m0 + mt * 16 + rr) * 256 + k0 + q * 8);
#pragma unroll
    for (int u = 0; u < 2; ++u) {
      short8 b = *(const short8*)(a2w + (size_t)(j * 64 + (ntb + u) * 16 + rr) * 256 + k0 + q * 8);
      mfma8(acc[u], a, b);
    }
  }
#pragma unroll
  for (int u = 0; u < 2; ++u) {
    int lc = (ntb + u) * 16 + rr;
    float bv = a2b[j * 64 + lc];
#pragma unroll
    for (int r = 0; r < 4; ++r) tile[mt * 16 + q * 4 + r][lc] = acc[u][r] + bv;
  }
  __syncthreads();
  const int c = (t * 4) & 63;
  for (int r = 0; r < 32; ++r) {
    int bp = m0 + r, b = bp / 224, p = bp % 224, l7 = p / 7, k7 = p % 7;
    float s = scales[2 * p];
    float4 v;
    v.x = tile[r][c] * s; v.y = tile[r][c + 1] * s;
    v.z = tile[r][c + 2] * s; v.w = tile[r][c + 3] * s;
    if (k7 < 6) {
      size_t base = ((size_t)((b * 192 + l7 * 6 + k7) * 16 + j)) * 4096 + z * 1024;
      *(float4*)(out0 + base + t * 4) = v;
    } else {
      size_t base = ((size_t)((b * 32 + l7) * 16 + j)) * 11008 + z * 2752;
      for (int i = t * 4; i < 2752; i += 1024) *(float4*)(out1 + base + i) = v;
    }
  }
}

// ---------------- dec2B + tile_B writes (out2 B_HID, out3 B_KV, out4 B_INT) ----------------
// grid (28, 16, 4): rb=32 bp-rows, j = c-group (c = 4j..4j+3), z = rep split.
__global__ __launch_bounds__(256) void dec2b_kernel(const u16* __restrict__ hB,
    const u16* __restrict__ b2w, const float* __restrict__ b2b, const float* __restrict__ scales,
    float* __restrict__ out2, float* __restrict__ out3, float* __restrict__ out4) {
  __shared__ float tile[32][68];
  const int rb = blockIdx.x, j = blockIdx.y, z = blockIdx.z;
  const int t = threadIdx.x, w = t >> 6, lane = t & 63;
  const int m0 = rb * 32;
  const int mt = w >> 1, ntb = (w & 1) * 2;
  const int rr = lane & 15, q = lane >> 4;
  floatx4 acc[2];
  acc[0] = (floatx4){0.f, 0.f, 0.f, 0.f};
  acc[1] = (floatx4){0.f, 0.f, 0.f, 0.f};
  for (int k0 = 0; k0 < 256; k0 += 32) {
    short8 a = *(const short8*)(hB + (size_t)(m0 + mt * 16 + rr) * 256 + k0 + q * 8);
#pragma unroll
    for (int u = 0; u < 2; ++u) {
      short8 b = *(const short8*)(b2w + (size_t)(j * 64 + (ntb + u) * 16 + rr) * 256 + k0 + q * 8);
      mfma8(acc[u], a, b);
    }
  }
#pragma unroll
  for (int u = 0; u < 2; ++u) {
    int lc = (ntb + u) * 16 + rr;
    float bv = b2b[j * 64 + lc];
#pragma unroll
    for (int r = 0; r < 4; ++r) tile[mt * 16 + q * 4 + r][lc] = acc[u][r] + bv;
  }
  __syncthreads();
  const int r16 = t & 15, c_l = (t >> 4) & 3, wv = t >> 6;
  for (int r = 0; r < 32; ++r) {
    int bp = m0 + r, b = bp / 224, p = bp % 224, l7 = p / 7, k7 = p % 7;
    float s = scales[2 * p + 1];
    float v = tile[r][c_l * 16 + r16] * s;
    if (k7 == 0 || k7 == 3 || k7 == 6) {
      size_t rowbase = (size_t)(b * 96 + l7 * 3 + k7 / 3) * 65536;
      for (int rep = z * 16 + wv; rep < z * 16 + 16; rep += 4)
        out2[rowbase + (size_t)(rep * 64 + j * 4 + c_l) * 16 + r16] = v;
    } else if (k7 <= 2) {
      size_t rowbase = (size_t)(b * 64 + l7 * 2 + (k7 - 1)) * 16384;
      int rep = z * 4 + wv;
      out3[rowbase + (size_t)(rep * 64 + j * 4 + c_l) * 16 + r16] = v;
    } else {
      size_t rowbase = (size_t)(b * 64 + l7 * 2 + (k7 - 4)) * 176128;
      for (int rep = z * 43 + wv; rep < z * 43 + 43; rep += 4)
        out4[rowbase + (size_t)(rep * 64 + j * 4 + c_l) * 16 + r16] = v;
    }
  }
}

extern "C" void kernel_launch(void* const* d_in, const int* in_sizes, int n_in,
                              void* d_out, int out_size, void* d_ws, size_t ws_size,
                              hipStream_t stream) {
  const int* ids     = (const int*)d_in[0];
  const int* mask    = (const int*)d_in[1];
  const float* emb   = (const float*)d_in[2];
  const float* qkv_w = (const float*)d_in[3];
  const float* qkv_b = (const float*)d_in[4];
  const float* out_w = (const float*)d_in[5];
  const float* out_b = (const float*)d_in[6];
  const float* ln1_g = (const float*)d_in[7];
  const float* ln1_b = (const float*)d_in[8];
  const float* ff1_w = (const float*)d_in[9];
  const float* ff1_b = (const float*)d_in[10];
  const float* ff2_w = (const float*)d_in[11];
  const float* ff2_b = (const float*)d_in[12];
  const float* ln2_g = (const float*)d_in[13];
  const float* ln2_b = (const float*)d_in[14];
  const float* proj_w = (const float*)d_in[15];
  const float* proj_b = (const float*)d_in[16];
  const float* a1_w = (const float*)d_in[17];
  const float* a1_b = (const float*)d_in[18];
  const float* a2_w = (const float*)d_in[19];
  const float* a2_b = (const float*)d_in[20];
  const float* b1_w = (const float*)d_in[21];
  const float* b1_b = (const float*)d_in[22];
  const float* b2_w = (const float*)d_in[23];
  const float* b2_b = (const float*)d_in[24];
  const float* scales = (const float*)d_in[25];

  u16* wb = (u16*)d_ws;
  u16* qkvw_b = wb + 0;        // 3*768*256  = 589824
  u16* outw_b = wb + 589824;   // 3*256*256  = 196608
  u16* ff1w_b = wb + 786432;   // 3*2048*256 = 1572864
  u16* ff2w_b = wb + 2359296;  // 3*256*2048 = 1572864
  u16* a1w_b  = wb + 3932160;  // 256*512    = 131072
  u16* a2w_b  = wb + 4063232;  // 1024*256   = 262144
  u16* b1w_b  = wb + 4325376;  // 131072
  u16* b2w_b  = wb + 4456448;  // 262144
  u16* qkvbf  = wb + 4718592;  // 512*768
  u16* obf    = wb + 5111808;  // 512*256
  u16* ffbf   = wb + 5242880;  // 512*2048
  u16* pebf   = wb + 6291456;  // 896*512
  u16* hAbf   = wb + 6750208;  // 896*256
  u16* hBbf   = wb + 6979584;  // 896*256
  float* xbuf   = (float*)(wb + 7208960);  // 512*256
  float* pooled = xbuf + 131072;           // 1024

  float* out = (float*)d_out;
  float* out0 = out;
  float* out1 = out + 50331648ull;
  float* out2 = out + 72876032ull;
  float* out3 = out + 98041856ull;
  float* out4 = out + 102236160ull;

  WConvArgs wa;
  wa.src[0] = qkv_w; wa.dst[0] = qkvw_b; wa.cnt[0] = 589824;
  wa.src[1] = out_w; wa.dst[1] = outw_b; wa.cnt[1] = 196608;
  wa.src[2] = ff1_w; wa.dst[2] = ff1w_b; wa.cnt[2] = 1572864;
  wa.src[3] = ff2_w; wa.dst[3] = ff2w_b; wa.cnt[3] = 1572864;
  wa.src[4] = a1_w;  wa.dst[4] = a1w_b;  wa.cnt[4] = 131072;
  wa.src[5] = a2_w;  wa.dst[5] = a2w_b;  wa.cnt[5] = 262144;
  wa.src[6] = b1_w;  wa.dst[6] = b1w_b;  wa.cnt[6] = 131072;
  wa.src[7] = b2_w;  wa.dst[7] = b2w_b;  wa.cnt[7] = 262144;
  wconv_kernel<<<1024, 256, 0, stream>>>(wa);

  embed_qkv_kernel<<<16, 256, 0, stream>>>(ids, emb, xbuf, qkvw_b, qkv_b, qkvbf);
  for (int l = 0; l < 3; ++l) {
    attn_kernel<<<512, 256, 0, stream>>>(qkvbf, mask, obf);
    post1_kernel<<<16, 256, 0, stream>>>(xbuf, obf, outw_b + l * 65536, out_b + l * 256,
                                         ln1_g + l * 256, ln1_b + l * 256,
                                         ff1w_b + l * 524288, ff1_b + l * 2048, ffbf);
    if (l < 2)
      post2_kernel<0><<<16, 256, 0, stream>>>(ffbf, ff2w_b + l * 524288, ff2_b + l * 256,
                                              ln2_g + l * 256, ln2_b + l * 256, xbuf,
                                              qkvw_b + (l + 1) * 196608, qkv_b + (l + 1) * 768,
                                              qkvbf);
    else
      post2_kernel<1><<<16, 256, 0, stream>>>(ffbf, ff2w_b + l * 524288, ff2_b + l * 256,
                                              ln2_g + l * 256, ln2_b + l * 256, xbuf,
                                              qkvw_b, qkv_b, qkvbf);
  }
  pool_kernel<<<4, 256, 0, stream>>>(xbuf, mask, pooled);
  proj_kernel<<<14336, 256, 0, stream>>>(pooled, proj_w, proj_b, pebf);
  dec1_kernel<<<dim3(28, 2), 256, 0, stream>>>(pebf, a1w_b, b1w_b, a1_b, b1_b, hAbf, hBbf);
  dec2a_kernel<<<dim3(28, 16, 4), 256, 0, stream>>>(hAbf, a2w_b, a2_b, scales, out0, out1);
  dec2b_kernel<<<dim3(28, 16, 4), 256, 0, stream>>>(hBbf, b2w_b, b2_b, scales, out2, out3, out4);
}

// Round 6
// 1160.523 us; speedup vs baseline: 1.1120x; 1.1120x over previous
//
#include <hip/hip_runtime.h>
#include <hip/hip_bf16.h>

typedef unsigned short u16;
typedef unsigned int u32;
typedef __attribute__((ext_vector_type(8))) short short8;
typedef __attribute__((ext_vector_type(4))) float floatx4;

__device__ __forceinline__ u16 f2bf(float f) {
  u32 x = __float_as_uint(f);
  x += 0x7FFFu + ((x >> 16) & 1u);
  return (u16)(x >> 16);
}
__device__ __forceinline__ float bf2f(u16 u) { return __uint_as_float(((u32)u) << 16); }
__device__ __forceinline__ u32 pk2(float lo, float hi) {
  return (u32)f2bf(lo) | ((u32)f2bf(hi) << 16);
}
__device__ __forceinline__ void mfma8(floatx4& acc, short8 a, short8 b) {
  acc = __builtin_amdgcn_mfma_f32_16x16x32_bf16(a, b, acc, 0, 0, 0);
}

// ============ round-4 proven GEMM: C = act(A_f32[M,K] @ W_f32[N,K]^T + bias) ============
// block 256 (4 waves), tile 64x64, K-step 32, LDS-staged + converted. SPLIT=1: partials.
template <int ACT, int SPLIT>
__global__ __launch_bounds__(256) void mfma_gemm_kernel(const float* __restrict__ A,
    const float* __restrict__ W, const float* __restrict__ bias, float* __restrict__ C,
    int M, int N, int K, int KS, int pstride) {
  __shared__ u16 Abf[64 * 32];
  __shared__ u16 Wbf[64 * 32];
  const int t = threadIdx.x;
  const int m0 = blockIdx.x * 64, n0 = blockIdx.y * 64;
  const int kz = blockIdx.z;
  const int srow = t >> 2, skc = (t & 3) * 8;
  const int w = t >> 6, lane = t & 63;
  const int q = lane >> 4, rr = lane & 15;
  floatx4 acc[4];
#pragma unroll
  for (int i = 0; i < 4; ++i) acc[i] = (floatx4){0.f, 0.f, 0.f, 0.f};
  const int kbeg = kz * KS, kend = kbeg + KS;
  for (int k0 = kbeg; k0 < kend; k0 += 32) {
    const float* ga = A + (size_t)(m0 + srow) * K + k0 + skc;
    const float* gw = W + (size_t)(n0 + srow) * K + k0 + skc;
    float4 a0 = *(const float4*)ga;
    float4 a1 = *(const float4*)(ga + 4);
    float4 w0 = *(const float4*)gw;
    float4 w1 = *(const float4*)(gw + 4);
    uint4 pa, pw;
    pa.x = pk2(a0.x, a0.y); pa.y = pk2(a0.z, a0.w);
    pa.z = pk2(a1.x, a1.y); pa.w = pk2(a1.z, a1.w);
    pw.x = pk2(w0.x, w0.y); pw.y = pk2(w0.z, w0.w);
    pw.z = pk2(w1.x, w1.y); pw.w = pk2(w1.z, w1.w);
    __syncthreads();
    *(uint4*)&Abf[srow * 32 + skc] = pa;
    *(uint4*)&Wbf[srow * 32 + skc] = pw;
    __syncthreads();
    short8 af = *(short8*)&Abf[(w * 16 + rr) * 32 + q * 8];
#pragma unroll
    for (int ct = 0; ct < 4; ++ct) {
      short8 bf = *(short8*)&Wbf[(ct * 16 + rr) * 32 + q * 8];
      acc[ct] = __builtin_amdgcn_mfma_f32_16x16x32_bf16(af, bf, acc[ct], 0, 0, 0);
    }
  }
  float* dst = SPLIT ? (C + (size_t)kz * pstride) : C;
#pragma unroll
  for (int ct = 0; ct < 4; ++ct) {
    int col = n0 + ct * 16 + rr;
#pragma unroll
    for (int r = 0; r < 4; ++r) {
      int row = m0 + w * 16 + q * 4 + r;
      float v = acc[ct][r];
      if (!SPLIT) {
        v += bias[col];
        if (ACT == 1) v = fmaxf(v, 0.f);
        if (ACT == 2) v = 0.5f * v * (1.f + erff(v * 0.70710678118654752f));
      }
      dst[(size_t)row * N + col] = v;
    }
  }
}

// ============ weight fp32->bf16 preconvert (encoder weights) ============
struct WConvArgs {
  const float* src[3];
  u16* dst[3];
  int cnt[3];
};
__global__ __launch_bounds__(256) void wconv_kernel(WConvArgs a) {
  int tid = blockIdx.x * 256 + threadIdx.x;
  int stride = gridDim.x * 256;
  for (int s = 0; s < 3; ++s) {
    const float* src = a.src[s];
    u16* dst = a.dst[s];
    int n4 = a.cnt[s] >> 2;
    for (int i = tid; i < n4; i += stride) {
      float4 v = ((const float4*)src)[i];
      ushort4 o;
      o.x = f2bf(v.x); o.y = f2bf(v.y); o.z = f2bf(v.z); o.w = f2bf(v.w);
      ((ushort4*)dst)[i] = o;
    }
  }
}

// ============ fused-encoder GEMM helper: C[32xN] = A(Albs) @ W^T, W bf16 [N][256] ============
// Albs[32][264] resident; Wlds[64][264] staged per 64-col block (coalesced, padded).
// Wave w owns cols nb*64 + w*16 + rr. Epilogue: RELU->fp32 dst (ldd), else bf16 dst.
template <int NB, int RELU, int BF16OUT>
__device__ __forceinline__ void gemm_from_albs(const u16* Albs, u16* Wlds,
    const u16* __restrict__ W, const float* __restrict__ bias, void* dst, int ldd,
    int m0, int t, int w, int lane) {
  const int rr = lane & 15, q = lane >> 4;
  for (int nb = 0; nb < NB; ++nb) {
#pragma unroll
    for (int i = 0; i < 8; ++i) {
      int idx = i * 256 + t, row = idx >> 5, col8 = (idx & 31) * 8;
      *(uint4*)&Wlds[row * 264 + col8] = *(const uint4*)&W[(size_t)(nb * 64 + row) * 256 + col8];
    }
    __syncthreads();
    floatx4 acc0 = (floatx4){0.f, 0.f, 0.f, 0.f};
    floatx4 acc1 = (floatx4){0.f, 0.f, 0.f, 0.f};
#pragma unroll
    for (int k0 = 0; k0 < 256; k0 += 32) {
      short8 a0 = *(const short8*)&Albs[rr * 264 + k0 + q * 8];
      short8 a1 = *(const short8*)&Albs[(16 + rr) * 264 + k0 + q * 8];
      short8 b = *(const short8*)&Wlds[(w * 16 + rr) * 264 + k0 + q * 8];
      mfma8(acc0, a0, b);
      mfma8(acc1, a1, b);
    }
    int col = nb * 64 + w * 16 + rr;
    float bv = bias[col];
#pragma unroll
    for (int mt = 0; mt < 2; ++mt) {
      floatx4 a = mt ? acc1 : acc0;
#pragma unroll
      for (int r = 0; r < 4; ++r) {
        int row = m0 + mt * 16 + q * 4 + r;
        float v = a[r] + bv;
        if (RELU) v = fmaxf(v, 0.f);
        if (BF16OUT)
          ((u16*)dst)[(size_t)row * ldd + col] = f2bf(v);
        else
          ((float*)dst)[(size_t)row * ldd + col] = v;
      }
    }
    __syncthreads();
  }
}

// ============ embed + QKV(layer 0) ============
__global__ __launch_bounds__(256) void embed_qkv_kernel(const int* __restrict__ ids,
    const float* __restrict__ emb, float* __restrict__ x, const u16* __restrict__ qkvw,
    const float* __restrict__ qkvb, u16* __restrict__ qkvbf) {
  __shared__ u16 Albs[32 * 264];
  __shared__ u16 Wlds[64 * 264];
  const int t = threadIdx.x, w = t >> 6, lane = t & 63;
  const int m0 = blockIdx.x * 32;
  for (int r = 0; r < 32; ++r) {
    float v = emb[(size_t)ids[m0 + r] * 256 + t];
    x[(size_t)(m0 + r) * 256 + t] = v;
    Albs[r * 264 + t] = f2bf(v);
  }
  __syncthreads();
  gemm_from_albs<12, 0, 1>(Albs, Wlds, qkvw, qkvb, qkvbf, 768, m0, t, w, lane);
}

// ============ attention (bf16 in/out, fp32 internal) — proven ============
__global__ __launch_bounds__(256) void attn_kernel(const u16* __restrict__ qkv,
    const int* __restrict__ mask, u16* __restrict__ o) {
  __shared__ float Klds[8192];
  __shared__ float Vlds[8192];
  const int blk = blockIdx.x;
  const int b = blk >> 7, h = (blk >> 5) & 3, qg = blk & 31;
  const int t = threadIdx.x;
  for (int i = t; i < 8192; i += 256) {
    int s = i >> 6, d = i & 63;
    size_t base = (size_t)(b * 128 + s) * 768 + h * 64 + d;
    Klds[(s << 6) + (d ^ (s & 31))] = bf2f(qkv[base + 256]);
    Vlds[i] = bf2f(qkv[base + 512]);
  }
  __syncthreads();
  const int wave = t >> 6, lane = t & 63;
  const int q = qg * 4 + wave;
  float qv = bf2f(qkv[(size_t)(b * 128 + q) * 768 + h * 64 + lane]);
  const int m0i = mask[b * 128 + lane];
  const int m1i = mask[b * 128 + 64 + lane];
  float s0 = 0.f, s1 = 0.f;
  const int sw = lane & 31;
  for (int d = 0; d < 64; ++d) {
    float qd = __shfl(qv, d);
    s0 += qd * Klds[(lane << 6) + (d ^ sw)];
    s1 += qd * Klds[((lane + 64) << 6) + (d ^ sw)];
  }
  s0 *= 0.125f; s1 *= 0.125f;
  if (m0i == 0) s0 = -1000000000.0f;
  if (m1i == 0) s1 = -1000000000.0f;
  float m = fmaxf(s0, s1);
  for (int off = 32; off; off >>= 1) m = fmaxf(m, __shfl_xor(m, off));
  float p0 = expf(s0 - m), p1 = expf(s1 - m);
  float sum = p0 + p1;
  for (int off = 32; off; off >>= 1) sum += __shfl_xor(sum, off);
  float rs = 1.f / sum;
  float acc = 0.f;
  for (int k = 0; k < 64; ++k) acc += __shfl(p0, k) * Vlds[(k << 6) + lane];
  for (int k = 0; k < 64; ++k) acc += __shfl(p1, k) * Vlds[((k + 64) << 6) + lane];
  o[(size_t)(b * 128 + q) * 256 + h * 64 + lane] = f2bf(acc * rs);
}

// ============ post1: out-proj + residual + LN1 + FF1(relu, fp32 out) ============
__global__ __launch_bounds__(256) void post1_kernel(float* __restrict__ x,
    const u16* __restrict__ obf, const u16* __restrict__ outw, const float* __restrict__ outb,
    const float* __restrict__ g1, const float* __restrict__ b1, const u16* __restrict__ ff1w,
    const float* __restrict__ ff1b, float* __restrict__ ff) {
  __shared__ u16 Albs[32 * 264];
  __shared__ char ubuf[64 * 264 * 2];  // Wlds (64x264 bf16) aliases S (32x264 f32)
  u16* Wlds = (u16*)ubuf;
  float* S = (float*)ubuf;
  const int t = threadIdx.x, w = t >> 6, lane = t & 63;
  const int rr = lane & 15, q = lane >> 4;
  const int m0 = blockIdx.x * 32;
#pragma unroll
  for (int i = 0; i < 4; ++i) {
    int idx = i * 256 + t, row = idx >> 5, col8 = (idx & 31) * 8;
    *(uint4*)&Albs[row * 264 + col8] = *(const uint4*)&obf[(size_t)(m0 + row) * 256 + col8];
  }
  __syncthreads();
  // out-proj: accumulate in registers (S aliases Wlds)
  floatx4 accP[4][2];
  for (int nb = 0; nb < 4; ++nb) {
#pragma unroll
    for (int i = 0; i < 8; ++i) {
      int idx = i * 256 + t, row = idx >> 5, col8 = (idx & 31) * 8;
      *(uint4*)&Wlds[row * 264 + col8] = *(const uint4*)&outw[(size_t)(nb * 64 + row) * 256 + col8];
    }
    __syncthreads();
    floatx4 a0v = (floatx4){0.f, 0.f, 0.f, 0.f};
    floatx4 a1v = (floatx4){0.f, 0.f, 0.f, 0.f};
#pragma unroll
    for (int k0 = 0; k0 < 256; k0 += 32) {
      short8 a0 = *(const short8*)&Albs[rr * 264 + k0 + q * 8];
      short8 a1 = *(const short8*)&Albs[(16 + rr) * 264 + k0 + q * 8];
      short8 b = *(const short8*)&Wlds[(w * 16 + rr) * 264 + k0 + q * 8];
      mfma8(a0v, a0, b);
      mfma8(a1v, a1, b);
    }
    accP[nb][0] = a0v;
    accP[nb][1] = a1v;
    __syncthreads();
  }
  // S = out-proj + bias + residual
#pragma unroll
  for (int nb = 0; nb < 4; ++nb) {
    int col = nb * 64 + w * 16 + rr;
    float bv = outb[col];
#pragma unroll
    for (int mt = 0; mt < 2; ++mt)
#pragma unroll
      for (int r = 0; r < 4; ++r) {
        int row = mt * 16 + q * 4 + r;
        S[row * 264 + col] = accP[nb][mt][r] + bv + x[(size_t)(m0 + row) * 256 + col];
      }
  }
  __syncthreads();
  // LN1 -> x (fp32) + Albs (bf16)
  {
    int j = t >> 3, s8 = t & 7;
    float sm = 0.f, sq = 0.f;
#pragma unroll
    for (int ci = 0; ci < 32; ++ci) {
      float v = S[j * 264 + ci * 8 + s8];
      sm += v; sq += v * v;
    }
    for (int off = 1; off < 8; off <<= 1) { sm += __shfl_xor(sm, off); sq += __shfl_xor(sq, off); }
    float mean = sm * (1.f / 256.f);
    float var = sq * (1.f / 256.f) - mean * mean;
    float inv = 1.f / sqrtf(fmaxf(var, 0.f) + 1e-5f);
#pragma unroll
    for (int ci = 0; ci < 32; ++ci) {
      int col = ci * 8 + s8;
      float v = (S[j * 264 + col] - mean) * inv * g1[col] + b1[col];
      x[(size_t)(m0 + j) * 256 + col] = v;
      Albs[j * 264 + col] = f2bf(v);
    }
  }
  __syncthreads();
  // FF1: relu(x_ln @ ff1w^T + b) -> ff fp32 (feeds proven split-K FF2)
  gemm_from_albs<32, 1, 0>(Albs, Wlds, ff1w, ff1b, ff, 2048, m0, t, w, lane);
}

// ============ post2b: reduce FF2 parts + bias + residual + LN2 (+ next QKV) ============
template <int LAST>
__global__ __launch_bounds__(256) void post2b_kernel(const float* __restrict__ parts,
    const float* __restrict__ ff2b, const float* __restrict__ g2, const float* __restrict__ b2,
    float* __restrict__ x, const u16* __restrict__ qkvw, const float* __restrict__ qkvb,
    u16* __restrict__ qkvbf) {
  __shared__ u16 Albs[32 * 264];
  __shared__ char ubuf[64 * 264 * 2];
  u16* Wlds = (u16*)ubuf;
  float* S = (float*)ubuf;
  const int t = threadIdx.x, w = t >> 6, lane = t & 63;
  const int m0 = blockIdx.x * 32;
  for (int e = t; e < 8192; e += 256) {
    int row = e >> 8, col = e & 255;
    size_t gi = (size_t)(m0 + row) * 256 + col;
    float v = ff2b[col] + x[gi];
#pragma unroll
    for (int p = 0; p < 8; ++p) v += parts[(size_t)p * 131072 + gi];
    S[row * 264 + col] = v;
  }
  __syncthreads();
  {
    int j = t >> 3, s8 = t & 7;
    float sm = 0.f, sq = 0.f;
#pragma unroll
    for (int ci = 0; ci < 32; ++ci) {
      float v = S[j * 264 + ci * 8 + s8];
      sm += v; sq += v * v;
    }
    for (int off = 1; off < 8; off <<= 1) { sm += __shfl_xor(sm, off); sq += __shfl_xor(sq, off); }
    float mean = sm * (1.f / 256.f);
    float var = sq * (1.f / 256.f) - mean * mean;
    float inv = 1.f / sqrtf(fmaxf(var, 0.f) + 1e-5f);
#pragma unroll
    for (int ci = 0; ci < 32; ++ci) {
      int col = ci * 8 + s8;
      float v = (S[j * 264 + col] - mean) * inv * g2[col] + b2[col];
      x[(size_t)(m0 + j) * 256 + col] = v;
      Albs[j * 264 + col] = f2bf(v);
    }
  }
  __syncthreads();
  if (!LAST)
    gemm_from_albs<12, 0, 1>(Albs, Wlds, qkvw, qkvb, qkvbf, 768, m0, t, w, lane);
}

// ============ pool / proj / tiles — round-4 proven ============
__global__ void pool_kernel(const float* __restrict__ x, const int* __restrict__ mask,
                            float* __restrict__ pooled) {
  int b = blockIdx.x, d = threadIdx.x;
  float s = 0.f, c = 0.f;
  for (int ss = 0; ss < 128; ++ss) {
    float m = (float)mask[b * 128 + ss];
    s += m * x[(size_t)(b * 128 + ss) * 256 + d];
    c += m;
  }
  pooled[b * 256 + d] = s / fmaxf(c, 1.f);
}

__global__ __launch_bounds__(256) void proj_kernel(const float* __restrict__ pooled,
    const float* __restrict__ W, const float* __restrict__ bias, float* __restrict__ pe) {
  __shared__ float pl[1024];
  int t = threadIdx.x;
  for (int i = t; i < 1024; i += 256) pl[i] = pooled[i];
  __syncthreads();
  int wave = t >> 6, lane = t & 63;
  int half = lane >> 5, sl = lane & 31;
  int row = blockIdx.x * 8 + wave * 2 + half;
  float4 w0 = *(const float4*)(W + (size_t)row * 256 + sl * 8);
  float4 w1 = *(const float4*)(W + (size_t)row * 256 + sl * 8 + 4);
  float a0, a1, a2, a3;
#pragma unroll
  for (int bb = 0; bb < 4; ++bb) {
    const float* pp = &pl[bb * 256 + sl * 8];
    float v = w0.x * pp[0] + w0.y * pp[1] + w0.z * pp[2] + w0.w * pp[3]
            + w1.x * pp[4] + w1.y * pp[5] + w1.z * pp[6] + w1.w * pp[7];
    if (bb == 0) a0 = v; else if (bb == 1) a1 = v; else if (bb == 2) a2 = v; else a3 = v;
  }
#pragma unroll
  for (int off = 1; off < 32; off <<= 1) {
    a0 += __shfl_xor(a0, off); a1 += __shfl_xor(a1, off);
    a2 += __shfl_xor(a2, off); a3 += __shfl_xor(a3, off);
  }
  if (sl == 0) {
    float bv = bias[row];
    pe[0 * 114688 + row] = a0 + bv;
    pe[1 * 114688 + row] = a1 + bv;
    pe[2 * 114688 + row] = a2 + bv;
    pe[3 * 114688 + row] = a3 + bv;
  }
}

__global__ __launch_bounds__(256) void tile_a_kernel(const float* __restrict__ Abase,
    const float* __restrict__ scales, float* __restrict__ out, int nI, int ind,
    int pdiv, int pmul, int padd) {
  int row = blockIdx.x;
  int r = row & 15, bi = row >> 4;
  int i = bi % nI, b = bi / nI;
  int p = (i / pdiv) * 7 + (i % pdiv) * pmul + padd;
  float s = scales[2 * p];
  __shared__ float chunk[64];
  int t = threadIdx.x;
  if (t < 64) chunk[t] = Abase[((size_t)(b * 224 + p) * 16 + r) * 64 + t] * s;
  __syncthreads();
  size_t ob = (size_t)row * ind;
  for (int u = t; u * 4 < ind; u += 256) {
    int c0 = u * 4;
    float4 ov = *(const float4*)&chunk[c0 & 63];
    *(float4*)(out + ob + c0) = ov;
  }
}

__global__ __launch_bounds__(256) void tile_b_kernel(const float* __restrict__ Bbase,
    const float* __restrict__ scales, float* __restrict__ out, int nI, int ind, int nchunks,
    int pdiv, int pmul, int padd) {
  int blk = blockIdx.x;
  int cc = blk % nchunks, bi = blk / nchunks;
  int i = bi % nI, b = bi / nI;
  int p = (i / pdiv) * 7 + (i % pdiv) * pmul + padd;
  float s = scales[2 * p + 1];
  __shared__ float chunk[1024];
  int t = threadIdx.x;
  for (int e = t; e < 1024; e += 256) chunk[e] = Bbase[(size_t)(b * 224 + p) * 1024 + e] * s;
  __syncthreads();
  int cchunk16 = (ind / nchunks) * 16;
  size_t ob = (size_t)bi * ind * 16 + (size_t)cc * cchunk16;
  for (int u = t; u * 4 < cchunk16; u += 256) {
    int e0 = u * 4;
    int cabs = (cc * cchunk16 + e0) >> 4;
    int src = ((cabs & 63) << 4) + (e0 & 15);
    float4 ov = *(const float4*)&chunk[src];
    *(float4*)(out + ob + e0) = ov;
  }
}

extern "C" void kernel_launch(void* const* d_in, const int* in_sizes, int n_in,
                              void* d_out, int out_size, void* d_ws, size_t ws_size,
                              hipStream_t stream) {
  const int* ids     = (const int*)d_in[0];
  const int* mask    = (const int*)d_in[1];
  const float* emb   = (const float*)d_in[2];
  const float* qkv_w = (const float*)d_in[3];
  const float* qkv_b = (const float*)d_in[4];
  const float* out_w = (const float*)d_in[5];
  const float* out_b = (const float*)d_in[6];
  const float* ln1_g = (const float*)d_in[7];
  const float* ln1_b = (const float*)d_in[8];
  const float* ff1_w = (const float*)d_in[9];
  const float* ff1_b = (const float*)d_in[10];
  const float* ff2_w = (const float*)d_in[11];
  const float* ff2_b = (const float*)d_in[12];
  const float* ln2_g = (const float*)d_in[13];
  const float* ln2_b = (const float*)d_in[14];
  const float* proj_w = (const float*)d_in[15];
  const float* proj_b = (const float*)d_in[16];
  const float* a1_w = (const float*)d_in[17];
  const float* a1_b = (const float*)d_in[18];
  const float* a2_w = (const float*)d_in[19];
  const float* a2_b = (const float*)d_in[20];
  const float* b1_w = (const float*)d_in[21];
  const float* b1_b = (const float*)d_in[22];
  const float* b2_w = (const float*)d_in[23];
  const float* b2_b = (const float*)d_in[24];
  const float* scales = (const float*)d_in[25];

  u16* wb = (u16*)d_ws;
  u16* qkvw_b = wb + 0;        // 3*768*256  = 589824
  u16* outw_b = wb + 589824;   // 3*256*256  = 196608
  u16* ff1w_b = wb + 786432;   // 3*2048*256 = 1572864
  u16* qkvbf  = wb + 2359296;  // 512*768 = 393216
  u16* obf    = wb + 2752512;  // 512*256 = 131072
  float* fw     = (float*)(wb + 2883584);
  float* xbuf   = fw;                // 512*256   = 131072
  float* ff     = fw + 131072;       // 512*2048  = 1048576
  float* pooled = fw + 1179648;      // 1024
  float* pe     = fw + 1180672;      // 896*512   = 458752
  float* hA     = fw + 1639424;      // 896*256   = 229376
  float* hB     = fw + 1868800;      // 229376
  float* Abase  = fw + 2098176;      // 896*1024  = 917504
  float* Bbase  = fw + 3015680;      // 917504
  float* parts  = fw + 3933184;      // 8*131072  = 1048576

  float* out = (float*)d_out;
  float* out0 = out;
  float* out1 = out + 50331648ull;
  float* out2 = out + 72876032ull;
  float* out3 = out + 98041856ull;
  float* out4 = out + 102236160ull;

  WConvArgs wa;
  wa.src[0] = qkv_w; wa.dst[0] = qkvw_b; wa.cnt[0] = 589824;
  wa.src[1] = out_w; wa.dst[1] = outw_b; wa.cnt[1] = 196608;
  wa.src[2] = ff1_w; wa.dst[2] = ff1w_b; wa.cnt[2] = 1572864;
  wconv_kernel<<<512, 256, 0, stream>>>(wa);

  embed_qkv_kernel<<<16, 256, 0, stream>>>(ids, emb, xbuf, qkvw_b, qkv_b, qkvbf);
  for (int l = 0; l < 3; ++l) {
    attn_kernel<<<512, 256, 0, stream>>>(qkvbf, mask, obf);
    post1_kernel<<<16, 256, 0, stream>>>(xbuf, obf, outw_b + l * 65536, out_b + l * 256,
                                         ln1_g + l * 256, ln1_b + l * 256,
                                         ff1w_b + l * 524288, ff1_b + l * 2048, ff);
    mfma_gemm_kernel<0, 1><<<dim3(8, 4, 8), 256, 0, stream>>>(
        ff, ff2_w + l * 524288, nullptr, parts, 512, 256, 2048, 256, 131072);
    if (l < 2)
      post2b_kernel<0><<<16, 256, 0, stream>>>(parts, ff2_b + l * 256, ln2_g + l * 256,
                                               ln2_b + l * 256, xbuf,
                                               qkvw_b + (l + 1) * 196608,
                                               qkv_b + (l + 1) * 768, qkvbf);
    else
      post2b_kernel<1><<<16, 256, 0, stream>>>(parts, ff2_b + l * 256, ln2_g + l * 256,
                                               ln2_b + l * 256, xbuf, qkvw_b, qkv_b, qkvbf);
  }
  pool_kernel<<<4, 256, 0, stream>>>(xbuf, mask, pooled);
  proj_kernel<<<14336, 256, 0, stream>>>(pooled, proj_w, proj_b, pe);

  // decoder: non-split K=512 with fused GELU epilogue (proven kernel, ACT=2)
  mfma_gemm_kernel<2, 0><<<dim3(14, 4), 256, 0, stream>>>(pe, a1_w, a1_b, hA,
                                                          896, 256, 512, 512, 0);
  mfma_gemm_kernel<0, 0><<<dim3(14, 16), 256, 0, stream>>>(hA, a2_w, a2_b, Abase,
                                                           896, 1024, 256, 256, 0);
  mfma_gemm_kernel<2, 0><<<dim3(14, 4), 256, 0, stream>>>(pe, b1_w, b1_b, hB,
                                                          896, 256, 512, 512, 0);
  mfma_gemm_kernel<0, 0><<<dim3(14, 16), 256, 0, stream>>>(hB, b2_w, b2_b, Bbase,
                                                           896, 1024, 256, 256, 0);

  tile_a_kernel<<<12288, 256, 0, stream>>>(Abase, scales, out0, 192, 4096, 6, 1, 0);
  tile_a_kernel<<<2048, 256, 0, stream>>>(Abase, scales, out1, 32, 11008, 1, 0, 6);
  tile_b_kernel<<<3072, 256, 0, stream>>>(Bbase, scales, out2, 96, 4096, 8, 3, 3, 0);
  tile_b_kernel<<<512, 256, 0, stream>>>(Bbase, scales, out3, 64, 1024, 2, 2, 1, 1);
  tile_b_kernel<<<2048, 256, 0, stream>>>(Bbase, scales, out4, 64, 11008, 8, 2, 1, 4);
}